// Round 1
// baseline (23.575 us; speedup 1.0000x reference)
//
#include <hip/hip_runtime.h>

#define BATCH 64
#define NBOX 8192
#define NCLS 91
#define MAX_PRED 300
#define NUM_SEL 8000

// One block per batch b. 256 threads (4 waves).
// Scans selected_indexes in chunks of 256, computes in-order per-batch ranks
// via ballot + wave prefix, gathers boxes/scores and scatters output rows.
// Tail rows [count, MAX_PRED) are zero-filled by the same block.
__global__ __launch_bounds__(256)
void pick_nms_kernel(const float* __restrict__ pred_boxes,
                     const float* __restrict__ pred_scores,
                     const int* __restrict__ sel,
                     float* __restrict__ out) {
    const int b    = blockIdx.x;
    const int tid  = threadIdx.x;
    const int lane = tid & 63;
    const int wid  = tid >> 6;

    __shared__ int wave_sums[4];
    __shared__ int running;
    if (tid == 0) running = 0;

    // Output layout (all float values, concatenated in reference return order):
    float* out_num     = out;                            // (64,1)
    float* out_boxes   = out + BATCH;                    // (64,300,4)
    float* out_scores  = out + BATCH + BATCH*MAX_PRED*4; // (64,300)
    float* out_classes = out + BATCH + BATCH*MAX_PRED*5; // (64,300) as float

    __syncthreads();

    for (int base = 0; base < NUM_SEL; base += 256) {
        const int i  = base + tid;
        const int bv = (i < NUM_SEL) ? sel[3*i] : -1;
        const bool flag = (bv == b);
        const unsigned long long mask = __ballot(flag);
        if (lane == 0) wave_sums[wid] = __popcll(mask);
        __syncthreads();  // wave_sums ready; `running` stable from prev iter

        int woff = 0;
        #pragma unroll
        for (int w = 0; w < 4; ++w)
            if (w < wid) woff += wave_sums[w];
        const int total = wave_sums[0] + wave_sums[1] + wave_sums[2] + wave_sums[3];
        const int wprefix = __popcll(mask & ((1ull << lane) - 1ull));
        const int rank = running + woff + wprefix;

        if (flag && rank < MAX_PRED) {
            const int lab = sel[3*i + 1];
            const int box = sel[3*i + 2];
            const float4 bx =
                *reinterpret_cast<const float4*>(pred_boxes + ((size_t)b*NBOX + box)*4);
            const float sc = pred_scores[((size_t)b*NBOX + box)*NCLS + lab];
            *reinterpret_cast<float4*>(out_boxes + ((size_t)b*MAX_PRED + rank)*4) = bx;
            out_scores[b*MAX_PRED + rank]  = sc;
            out_classes[b*MAX_PRED + rank] = (float)lab;
        }
        __syncthreads();          // all reads of running/wave_sums done
        if (tid == 0) running += total;
        // next iteration's first __syncthreads() publishes `running`
    }

    __syncthreads();
    const int cnt = running;

    // Zero-fill unwritten tail rows so every output element is written each call.
    const int start = (cnt < MAX_PRED) ? cnt : MAX_PRED;
    for (int r = start + tid; r < MAX_PRED; r += 256) {
        *reinterpret_cast<float4*>(out_boxes + ((size_t)b*MAX_PRED + r)*4) =
            make_float4(0.f, 0.f, 0.f, 0.f);
        out_scores[b*MAX_PRED + r]  = 0.f;
        out_classes[b*MAX_PRED + r] = 0.f;
    }
    if (tid == 0) out_num[b] = (float)cnt;
}

extern "C" void kernel_launch(void* const* d_in, const int* in_sizes, int n_in,
                              void* d_out, int out_size, void* d_ws, size_t ws_size,
                              hipStream_t stream) {
    const float* pred_boxes  = (const float*)d_in[0];
    const float* pred_scores = (const float*)d_in[1];
    const int*   sel         = (const int*)d_in[2];
    float* out = (float*)d_out;

    pick_nms_kernel<<<dim3(BATCH), dim3(256), 0, stream>>>(
        pred_boxes, pred_scores, sel, out);
}

// Round 2
// 17.126 us; speedup vs baseline: 1.3766x; 1.3766x over previous
//
#include <hip/hip_runtime.h>

#define BATCH 64
#define NBOX 8192
#define NCLS 91
#define MAX_PRED 300
#define NUM_SEL 8000
#define NWORDS 125   // NUM_SEL / 64

// One block per batch b, 256 threads (4 waves).
// Phase A: all 8000 batch-indices loaded with fully-unrolled independent loads
//          (one memory round-trip), ballot'ed into a 125-word bitmask in LDS.
// Phase B: shfl-based prefix scan over word popcounts (no per-chunk barriers).
// Phase C: matching entries compute exact in-order rank from the bitmask and
//          gather/scatter their output row; tail rows zero-filled.
__global__ __launch_bounds__(256)
void pick_nms_kernel(const float* __restrict__ pred_boxes,
                     const float* __restrict__ pred_scores,
                     const int* __restrict__ sel,
                     float* __restrict__ out) {
    const int b    = blockIdx.x;
    const int tid  = threadIdx.x;
    const int lane = tid & 63;
    const int wid  = tid >> 6;

    __shared__ unsigned long long masks[NWORDS];
    __shared__ int excl[NWORDS];
    __shared__ int wave_tot[4];

    // Output layout (concatenated tuple, all as float):
    float* out_num     = out;                            // (64,1)
    float* out_boxes   = out + BATCH;                    // (64,300,4)
    float* out_scores  = out + BATCH + BATCH*MAX_PRED*4; // (64,300)
    float* out_classes = out + BATCH + BATCH*MAX_PRED*5; // (64,300) as float

    // ---- Phase A: load all b-values (32 per thread), fully unrolled ----
    int bv[32];
    #pragma unroll
    for (int k = 0; k < 32; ++k) {
        const int i = k * 256 + tid;
        bv[k] = (i < NUM_SEL) ? sel[3 * i] : -1;
    }
    #pragma unroll
    for (int k = 0; k < 32; ++k) {
        const unsigned long long m = __ballot(bv[k] == b);
        const int w = k * 4 + wid;
        if (lane == 0 && w < NWORDS) masks[w] = m;
    }
    __syncthreads();

    // ---- Phase B: exclusive prefix over word popcounts ----
    // Words 0..124 live in threads 0..124 (waves 0-1); waves 2-3 scan zeros.
    const int mypc = (tid < NWORDS) ? __popcll(masks[tid]) : 0;
    int incl = mypc;
    #pragma unroll
    for (int d = 1; d < 64; d <<= 1) {
        const int n = __shfl_up(incl, d, 64);
        if (lane >= d) incl += n;
    }
    if (lane == 63) wave_tot[wid] = incl;
    __syncthreads();
    int woff = 0;
    #pragma unroll
    for (int w = 0; w < 4; ++w)
        if (w < wid) woff += wave_tot[w];
    if (tid < NWORDS) excl[tid] = woff + incl - mypc;
    const int cnt = wave_tot[0] + wave_tot[1];   // words only span waves 0-1
    __syncthreads();

    // ---- Phase C: gather + scatter matching rows ----
    const unsigned long long lane_mask = (1ull << lane) - 1ull;
    #pragma unroll
    for (int k = 0; k < 32; ++k) {
        if (bv[k] == b) {
            const int i = k * 256 + tid;
            const int w = k * 4 + wid;
            const int rank = excl[w] + __popcll(masks[w] & lane_mask);
            if (rank < MAX_PRED) {
                const int lab = sel[3 * i + 1];
                const int box = sel[3 * i + 2];
                const float4 bx =
                    *reinterpret_cast<const float4*>(pred_boxes + ((size_t)b*NBOX + box)*4);
                const float sc = pred_scores[((size_t)b*NBOX + box)*NCLS + lab];
                *reinterpret_cast<float4*>(out_boxes + ((size_t)b*MAX_PRED + rank)*4) = bx;
                out_scores[b*MAX_PRED + rank]  = sc;
                out_classes[b*MAX_PRED + rank] = (float)lab;
            }
        }
    }

    // ---- Tail fill: zero unwritten rows (harness poisons d_out once) ----
    const int start = (cnt < MAX_PRED) ? cnt : MAX_PRED;
    for (int r = start + tid; r < MAX_PRED; r += 256) {
        *reinterpret_cast<float4*>(out_boxes + ((size_t)b*MAX_PRED + r)*4) =
            make_float4(0.f, 0.f, 0.f, 0.f);
        out_scores[b*MAX_PRED + r]  = 0.f;
        out_classes[b*MAX_PRED + r] = 0.f;
    }
    if (tid == 0) out_num[b] = (float)cnt;
}

extern "C" void kernel_launch(void* const* d_in, const int* in_sizes, int n_in,
                              void* d_out, int out_size, void* d_ws, size_t ws_size,
                              hipStream_t stream) {
    const float* pred_boxes  = (const float*)d_in[0];
    const float* pred_scores = (const float*)d_in[1];
    const int*   sel         = (const int*)d_in[2];
    float* out = (float*)d_out;

    pick_nms_kernel<<<dim3(BATCH), dim3(256), 0, stream>>>(
        pred_boxes, pred_scores, sel, out);
}

// Round 3
// 11.044 us; speedup vs baseline: 2.1347x; 1.5507x over previous
//
#include <hip/hip_runtime.h>

#define BATCH 64
#define NBOX 8192
#define NCLS 91
#define MAX_PRED 300
#define NUM_SEL 8000
#define NWORDS 125   // NUM_SEL / 64

// One block per batch b, 256 threads (4 waves).
// Phase A: all 8000 batch-indices loaded fully-unrolled (one memory round-trip),
//          ballot'ed into a 125-word bitmask in LDS.
// Phase B: shfl prefix scan over word popcounts -> excl[] (exclusive offsets).
// Phase C: ALU/LDS only — matching entries write their entry index to perm[rank].
// Phase D: one thread per output row r: single independent gather+store chain.
__global__ __launch_bounds__(256)
void pick_nms_kernel(const float* __restrict__ pred_boxes,
                     const float* __restrict__ pred_scores,
                     const int* __restrict__ sel,
                     float* __restrict__ out) {
    const int b    = blockIdx.x;
    const int tid  = threadIdx.x;
    const int lane = tid & 63;
    const int wid  = tid >> 6;

    __shared__ unsigned long long masks[NWORDS];
    __shared__ int excl[NWORDS];
    __shared__ int wave_tot[4];
    __shared__ int perm[MAX_PRED];

    // Output layout (concatenated tuple, all as float):
    float* out_num     = out;                            // (64,1)
    float* out_boxes   = out + BATCH;                    // (64,300,4)
    float* out_scores  = out + BATCH + BATCH*MAX_PRED*4; // (64,300)
    float* out_classes = out + BATCH + BATCH*MAX_PRED*5; // (64,300) as float

    // ---- Phase A: load all b-values (32 per thread), fully unrolled ----
    int bv[32];
    #pragma unroll
    for (int k = 0; k < 32; ++k) {
        const int i = k * 256 + tid;
        bv[k] = (i < NUM_SEL) ? sel[3 * i] : -1;
    }
    #pragma unroll
    for (int k = 0; k < 32; ++k) {
        const unsigned long long m = __ballot(bv[k] == b);
        const int w = k * 4 + wid;
        if (lane == 0 && w < NWORDS) masks[w] = m;
    }
    __syncthreads();

    // ---- Phase B: exclusive prefix over word popcounts (words in waves 0-1) ----
    const int mypc = (tid < NWORDS) ? __popcll(masks[tid]) : 0;
    int incl = mypc;
    #pragma unroll
    for (int d = 1; d < 64; d <<= 1) {
        const int n = __shfl_up(incl, d, 64);
        if (lane >= d) incl += n;
    }
    if (lane == 63) wave_tot[wid] = incl;
    __syncthreads();
    const int woff = (wid == 1) ? wave_tot[0] : 0;   // excl only used for tid<125
    if (tid < NWORDS) excl[tid] = woff + incl - mypc;
    const int cnt = wave_tot[0] + wave_tot[1];
    __syncthreads();

    // ---- Phase C: write rank -> entry-index permutation (no global memory ops) ----
    const unsigned long long lane_mask = (1ull << lane) - 1ull;
    #pragma unroll
    for (int k = 0; k < 32; ++k) {
        const unsigned long long m = __ballot(bv[k] == b);
        if (bv[k] == b) {
            const int w = k * 4 + wid;
            const int rank = excl[w] + __popcll(m & lane_mask);
            if (rank < MAX_PRED) perm[rank] = k * 256 + tid;
        }
    }
    __syncthreads();

    // ---- Phase D: one thread per output row; single gather chain each ----
    const int lim = (cnt < MAX_PRED) ? cnt : MAX_PRED;
    #pragma unroll
    for (int rr = 0; rr < 2; ++rr) {
        const int r = tid + rr * 256;
        if (r < MAX_PRED) {
            float4 bx = make_float4(0.f, 0.f, 0.f, 0.f);
            float sc = 0.f, cls = 0.f;
            if (r < lim) {
                const int i   = perm[r];
                const int lab = sel[3 * i + 1];
                const int box = sel[3 * i + 2];
                bx  = *reinterpret_cast<const float4*>(pred_boxes + ((size_t)b*NBOX + box)*4);
                sc  = pred_scores[((size_t)b*NBOX + box)*NCLS + lab];
                cls = (float)lab;
            }
            *reinterpret_cast<float4*>(out_boxes + ((size_t)b*MAX_PRED + r)*4) = bx;
            out_scores[b*MAX_PRED + r]  = sc;
            out_classes[b*MAX_PRED + r] = cls;
        }
    }
    if (tid == 0) out_num[b] = (float)cnt;
}

extern "C" void kernel_launch(void* const* d_in, const int* in_sizes, int n_in,
                              void* d_out, int out_size, void* d_ws, size_t ws_size,
                              hipStream_t stream) {
    const float* pred_boxes  = (const float*)d_in[0];
    const float* pred_scores = (const float*)d_in[1];
    const int*   sel         = (const int*)d_in[2];
    float* out = (float*)d_out;

    pick_nms_kernel<<<dim3(BATCH), dim3(256), 0, stream>>>(
        pred_boxes, pred_scores, sel, out);
}

// Round 4
// 9.770 us; speedup vs baseline: 2.4131x; 1.1305x over previous
//
#include <hip/hip_runtime.h>

#define BATCH 64
#define NBOX 8192
#define NCLS 91
#define MAX_PRED 300
#define NUM_SEL 8000
#define NWORDS 125   // NUM_SEL / 64
#define NT 512       // threads per block (8 waves)
#define KCH 16       // ceil(NUM_SEL / NT)

struct __align__(4) Int3 { int x, y, z; };

// One block per batch b, 512 threads (8 waves).
// Phase A: each thread loads 16 full sel rows (dwordx3) -> b,lab,box in regs;
//          ballots the b-match bits into a 125-word bitmask in LDS.
// Phase B: wave 0 alone scans word popcounts (2 words/lane, shfl scan) -> excl, cnt.
// Phase C: matching entries write packed (lab,box) into lb[rank] in LDS (no global ops).
// Phase D: thread r (<300) does one independent gather chain + store; tail rows zeroed.
__global__ __launch_bounds__(NT)
void pick_nms_kernel(const float* __restrict__ pred_boxes,
                     const float* __restrict__ pred_scores,
                     const Int3* __restrict__ sel,
                     float* __restrict__ out) {
    const int b    = blockIdx.x;
    const int tid  = threadIdx.x;
    const int lane = tid & 63;
    const int wid  = tid >> 6;

    __shared__ unsigned long long masks[NWORDS + 1]; // +1: scan reads word 125 safely
    __shared__ int  excl[NWORDS + 1];
    __shared__ int2 lb[MAX_PRED];
    __shared__ int  cnt_s;

    // Output layout (concatenated tuple, all as float):
    float* out_num     = out;                            // (64,1)
    float* out_boxes   = out + BATCH;                    // (64,300,4)
    float* out_scores  = out + BATCH + BATCH*MAX_PRED*4; // (64,300)
    float* out_classes = out + BATCH + BATCH*MAX_PRED*5; // (64,300) as float

    if (tid < 2) masks[NWORDS + tid - 1] = 0ull;  // zero word 124.. (124 real, 125 pad)
    // (word 124 is real; only pad word 125 must be 0 — masks[125]=0 via tid==1; tid==0
    //  writing masks[124]=0 is fine because k-loop below overwrites all real words)

    // ---- Phase A: load 16 sel rows per thread, ballot into masks ----
    int bv[KCH], lab[KCH], box[KCH];
    #pragma unroll
    for (int k = 0; k < KCH; ++k) {
        const int i = k * NT + tid;
        if (i < NUM_SEL) {
            const Int3 v = sel[i];
            bv[k] = v.x; lab[k] = v.y; box[k] = v.z;
        } else {
            bv[k] = -1; lab[k] = 0; box[k] = 0;
        }
    }
    #pragma unroll
    for (int k = 0; k < KCH; ++k) {
        const unsigned long long m = __ballot(bv[k] == b);
        const int w = k * 8 + wid;                 // 512 threads = 8 waves
        if (lane == 0 && w < NWORDS) masks[w] = m;
    }
    __syncthreads();

    // ---- Phase B: wave-0-only exclusive scan over word popcounts ----
    if (wid == 0) {
        const int t = lane;                         // handles words 2t, 2t+1
        const int p0 = (2*t     < NWORDS) ? __popcll(masks[2*t])     : 0;
        const int p1 = (2*t + 1 < NWORDS) ? __popcll(masks[2*t + 1]) : 0;
        int incl = p0 + p1;
        #pragma unroll
        for (int d = 1; d < 64; d <<= 1) {
            const int n = __shfl_up(incl, d, 64);
            if (t >= d) incl += n;
        }
        const int e0 = incl - p1 - p0;
        if (2*t < NWORDS)     excl[2*t]     = e0;
        if (2*t + 1 < NWORDS) excl[2*t + 1] = e0 + p0;
        const int total = __shfl(incl, 62, 64);     // word 124 lives in lane 62
        if (t == 0) cnt_s = total;
    }
    __syncthreads();
    const int cnt = cnt_s;

    // ---- Phase C: matching entries write (lab,box) into lb[rank] (LDS only) ----
    const unsigned long long lane_mask = (1ull << lane) - 1ull;
    #pragma unroll
    for (int k = 0; k < KCH; ++k) {
        const unsigned long long m = __ballot(bv[k] == b);
        if (bv[k] == b) {
            const int w = k * 8 + wid;
            const int rank = excl[w] + __popcll(m & lane_mask);
            if (rank < MAX_PRED) lb[rank] = make_int2(lab[k], box[k]);
        }
    }
    __syncthreads();

    // ---- Phase D: one thread per output row; single gather chain each ----
    const int lim = (cnt < MAX_PRED) ? cnt : MAX_PRED;
    if (tid < MAX_PRED) {
        const int r = tid;
        float4 bx = make_float4(0.f, 0.f, 0.f, 0.f);
        float sc = 0.f, cls = 0.f;
        if (r < lim) {
            const int2 v = lb[r];
            bx  = *reinterpret_cast<const float4*>(pred_boxes + ((size_t)b*NBOX + v.y)*4);
            sc  = pred_scores[((size_t)b*NBOX + v.y)*NCLS + v.x];
            cls = (float)v.x;
        }
        *reinterpret_cast<float4*>(out_boxes + ((size_t)b*MAX_PRED + r)*4) = bx;
        out_scores[b*MAX_PRED + r]  = sc;
        out_classes[b*MAX_PRED + r] = cls;
    }
    if (tid == 0) out_num[b] = (float)cnt;
}

extern "C" void kernel_launch(void* const* d_in, const int* in_sizes, int n_in,
                              void* d_out, int out_size, void* d_ws, size_t ws_size,
                              hipStream_t stream) {
    const float* pred_boxes  = (const float*)d_in[0];
    const float* pred_scores = (const float*)d_in[1];
    const Int3*  sel         = (const Int3*)d_in[2];
    float* out = (float*)d_out;

    pick_nms_kernel<<<dim3(BATCH), dim3(NT), 0, stream>>>(
        pred_boxes, pred_scores, sel, out);
}